// Round 9
// baseline (38.162 us; speedup 1.0000x reference)
//
#include <hip/hip_runtime.h>
#include <math.h>

#define BLOCK 256
#define MAXT  64

// MEASUREMENT ROUND: exact R2 kernel (best known, 22.8us), but rpn_main is
// launched TWICE into the same partials buffer (idempotent: identical values
// written twice; rpn_final runs after both). dur(R9) - dur(R2) = one
// warm-cache rpn_main replay -- decomposes the 22.8us into loop-time vs
// overhead, which 4 rounds of structural guessing failed to do.
__global__ void __launch_bounds__(BLOCK)
rpn_main(const float* __restrict__ reg,
         const float* __restrict__ cls,
         const float* __restrict__ anchors,
         const float* __restrict__ targets,
         float* __restrict__ partials,   // [nblk * 3]
         int A, int B, int T) {
    const int halfA = A >> 1;
    const int blocksPerB = halfA / BLOCK;            // A/2 divisible by BLOCK here
    const int b = blockIdx.x / blocksPerB;
    const int q = (blockIdx.x - b * blocksPerB) * BLOCK + threadIdx.x;

    __shared__ float4 s_box[MAXT];
    __shared__ float  s_area[MAXT];
    if (threadIdx.x < T) {
        const float4 t4 = reinterpret_cast<const float4*>(targets)[b * T + threadIdx.x];
        s_box[threadIdx.x]  = t4;
        s_area[threadIdx.x] = (t4.z - t4.x) * (t4.w - t4.y);
    }
    __syncthreads();

    const int a0 = q;
    const int a1 = q + halfA;
    const float4 anc0 = reinterpret_cast<const float4*>(anchors)[a0];
    const float4 anc1 = reinterpret_cast<const float4*>(anchors)[a1];
    const float sa0 = (anc0.z - anc0.x) * (anc0.w - anc0.y);
    const float sa1 = (anc1.z - anc1.x) * (anc1.w - anc1.y);

    float bn0 = 0.f, bd0 = 1.f, bn1 = 0.f, bd1 = 1.f;
    int bt0 = 0, bt1 = 0;

    #pragma unroll 8
    for (int t = 0; t < T; ++t) {
        const float4 tb = s_box[t];
        const float  st = s_area[t];
        // anchor 0
        {
            const float iw = fmaxf(fminf(tb.z, anc0.z) - fmaxf(tb.x, anc0.x), 0.f);
            const float ih = fmaxf(fminf(tb.w, anc0.w) - fmaxf(tb.y, anc0.y), 0.f);
            const float n = iw * ih;
            const float d = sa0 + st;
            if (n * bd0 > bn0 * d) { bn0 = n; bd0 = d; bt0 = t; }  // first-max
        }
        // anchor 1
        {
            const float iw = fmaxf(fminf(tb.z, anc1.z) - fmaxf(tb.x, anc1.x), 0.f);
            const float ih = fmaxf(fminf(tb.w, anc1.w) - fmaxf(tb.y, anc1.y), 0.f);
            const float n = iw * ih;
            const float d = sa1 + st;
            if (n * bd1 > bn1 * d) { bn1 = n; bd1 = d; bt1 = t; }
        }
    }

    float bce = 0.f, sl1 = 0.f, npos = 0.f;

    const int base = b * A;
    const float c0 = cls[base + a0];
    const float c1 = cls[base + a1];
    const float pos0 = (3.f * bn0 > bd0) ? 1.f : 0.f;
    const float pos1 = (3.f * bn1 > bd1) ? 1.f : 0.f;
    // stable softplus, matches jax.nn.softplus
    bce  = (fmaxf(c0, 0.f) + log1pf(expf(-fabsf(c0)))) - c0 * pos0;
    bce += (fmaxf(c1, 0.f) + log1pf(expf(-fabsf(c1)))) - c1 * pos1;
    npos = pos0 + pos1;

    if (pos0 != 0.f) {
        const float4 r  = reinterpret_cast<const float4*>(reg)[base + a0];
        const float4 tb = s_box[bt0];
        float e, ae;
        e = r.x - (tb.x - anc0.x); ae = fabsf(e); sl1 += (ae < 1.f) ? 0.5f * e * e : ae - 0.5f;
        e = r.y - (tb.y - anc0.y); ae = fabsf(e); sl1 += (ae < 1.f) ? 0.5f * e * e : ae - 0.5f;
        e = r.z - (tb.z - anc0.z); ae = fabsf(e); sl1 += (ae < 1.f) ? 0.5f * e * e : ae - 0.5f;
        e = r.w - (tb.w - anc0.w); ae = fabsf(e); sl1 += (ae < 1.f) ? 0.5f * e * e : ae - 0.5f;
    }
    if (pos1 != 0.f) {
        const float4 r  = reinterpret_cast<const float4*>(reg)[base + a1];
        const float4 tb = s_box[bt1];
        float e, ae;
        e = r.x - (tb.x - anc1.x); ae = fabsf(e); sl1 += (ae < 1.f) ? 0.5f * e * e : ae - 0.5f;
        e = r.y - (tb.y - anc1.y); ae = fabsf(e); sl1 += (ae < 1.f) ? 0.5f * e * e : ae - 0.5f;
        e = r.z - (tb.z - anc1.z); ae = fabsf(e); sl1 += (ae < 1.f) ? 0.5f * e * e : ae - 0.5f;
        e = r.w - (tb.w - anc1.w); ae = fabsf(e); sl1 += (ae < 1.f) ? 0.5f * e * e : ae - 0.5f;
    }

    // deterministic block reduction: wave64 shuffle then cross-wave LDS
    for (int off = 32; off > 0; off >>= 1) {
        bce  += __shfl_down(bce,  off, 64);
        sl1  += __shfl_down(sl1,  off, 64);
        npos += __shfl_down(npos, off, 64);
    }
    __shared__ float w_bce[BLOCK / 64], w_sl1[BLOCK / 64], w_np[BLOCK / 64];
    const int lane = threadIdx.x & 63, wid = threadIdx.x >> 6;
    if (lane == 0) { w_bce[wid] = bce; w_sl1[wid] = sl1; w_np[wid] = npos; }
    __syncthreads();
    if (threadIdx.x == 0) {
        float tb_ = 0.f, ts_ = 0.f, tn_ = 0.f;
        for (int w = 0; w < BLOCK / 64; ++w) {
            tb_ += w_bce[w]; ts_ += w_sl1[w]; tn_ += w_np[w];
        }
        partials[blockIdx.x * 3 + 0] = tb_;
        partials[blockIdx.x * 3 + 1] = ts_;
        partials[blockIdx.x * 3 + 2] = tn_;
    }
}

// Kernel 2: single block, double-precision deterministic final reduce.
__global__ void __launch_bounds__(256)
rpn_final(const float* __restrict__ partials, int nblk,
          float* __restrict__ out, int BA) {
    double b = 0.0, s = 0.0, n = 0.0;
    for (int i = threadIdx.x; i < nblk; i += 256) {
        b += (double)partials[i * 3 + 0];
        s += (double)partials[i * 3 + 1];
        n += (double)partials[i * 3 + 2];
    }
    __shared__ double sb[256], ss[256], sn[256];
    sb[threadIdx.x] = b; ss[threadIdx.x] = s; sn[threadIdx.x] = n;
    __syncthreads();
    for (int off = 128; off > 0; off >>= 1) {
        if (threadIdx.x < off) {
            sb[threadIdx.x] += sb[threadIdx.x + off];
            ss[threadIdx.x] += ss[threadIdx.x + off];
            sn[threadIdx.x] += sn[threadIdx.x + off];
        }
        __syncthreads();
    }
    if (threadIdx.x == 0) {
        const double npos = sn[0];
        const double denom = npos > 1.0 ? npos : 1.0;
        const double reg_loss = (npos > 0.0) ? (ss[0] / denom) : 0.0;
        out[0] = (float)(sb[0] / (double)BA);       // cls_loss (mean BCE)
        out[1] = (float)(reg_loss * 0.25);          // reg_loss / 4
    }
}

extern "C" void kernel_launch(void* const* d_in, const int* in_sizes, int n_in,
                              void* d_out, int out_size, void* d_ws, size_t ws_size,
                              hipStream_t stream) {
    const float* reg     = (const float*)d_in[0];
    const float* cls     = (const float*)d_in[1];
    const float* anchors = (const float*)d_in[2];
    const float* targets = (const float*)d_in[3];
    float* out = (float*)d_out;

    const int A = in_sizes[2] / 4;          // anchors [A,4]
    const int B = in_sizes[1] / A;          // cls [B,A]
    const int T = in_sizes[3] / (B * 4);    // targets [B,T,4]
    const int BA = B * A;
    const int nblk = (B * (A / 2)) / BLOCK; // 768 for this shape

    float* partials = (float*)d_ws;         // nblk*3 floats, overwritten every call

    // Launch main TWICE (idempotent writes) to measure one warm replay's cost
    // as dur(R9) - dur(R2).
    rpn_main<<<nblk, BLOCK, 0, stream>>>(reg, cls, anchors, targets,
                                         partials, A, B, T);
    rpn_main<<<nblk, BLOCK, 0, stream>>>(reg, cls, anchors, targets,
                                         partials, A, B, T);
    rpn_final<<<1, 256, 0, stream>>>(partials, nblk, out, BA);
}

// Round 10
// 23.964 us; speedup vs baseline: 1.5925x; 1.5925x over previous
//
#include <hip/hip_runtime.h>
#include <math.h>

#define BLOCK 256

// R10: single-variable experiment vs R2 (22.8us baseline).
// Identical structure/grid (768 blocks, 2 anchors/thread, same final kernel);
// ONLY the in-loop target fetch changes: LDS broadcast -> wave-uniform
// pointer load (s_load_dwordx4 through the scalar K$ pipe), area recomputed
// in VALU. No target LDS staging, no pre-loop __syncthreads. Tests whether
// the per-t LDS/lgkmcnt round-trip is the structural stall that keeps the
// warm main kernel at 15.3us (R9 measurement) vs its ~5us issue floor.
// Division-free: iou=n/(d-n) monotone in n/d => cross-mult compare
// (strict > == first-max argmax); max_iou>0.5 <=> 3n>d.
__global__ void __launch_bounds__(BLOCK)
rpn_main(const float* __restrict__ reg,
         const float* __restrict__ cls,
         const float* __restrict__ anchors,
         const float* __restrict__ targets,
         float* __restrict__ partials,   // [nblk * 3]
         int A, int B, int T) {
    const int halfA = A >> 1;
    const int blocksPerB = halfA / BLOCK;            // exact for this shape
    const int b = blockIdx.x / blocksPerB;           // wave-uniform
    const int q = (blockIdx.x - b * blocksPerB) * BLOCK + threadIdx.x;

    const int a0 = q;
    const int a1 = q + halfA;
    const float4 anc0 = reinterpret_cast<const float4*>(anchors)[a0];
    const float4 anc1 = reinterpret_cast<const float4*>(anchors)[a1];
    const float sa0 = (anc0.z - anc0.x) * (anc0.w - anc0.y);
    const float sa1 = (anc1.z - anc1.x) * (anc1.w - anc1.y);

    // wave-uniform target base pointer -> scalar loads in the hot loop
    const float4* __restrict__ tgt4 = reinterpret_cast<const float4*>(targets) + b * T;

    float bn0 = 0.f, bd0 = 1.f, bn1 = 0.f, bd1 = 1.f;
    int bt0 = 0, bt1 = 0;

    #pragma unroll 8
    for (int t = 0; t < T; ++t) {
        const float4 tb = tgt4[t];                        // uniform -> s_load_dwordx4
        const float  st = (tb.z - tb.x) * (tb.w - tb.y);  // VALU, shared by 2 anchors
        // anchor 0
        {
            const float iw = fmaxf(fminf(tb.z, anc0.z) - fmaxf(tb.x, anc0.x), 0.f);
            const float ih = fmaxf(fminf(tb.w, anc0.w) - fmaxf(tb.y, anc0.y), 0.f);
            const float n = iw * ih;
            const float d = sa0 + st;
            if (n * bd0 > bn0 * d) { bn0 = n; bd0 = d; bt0 = t; }  // first-max
        }
        // anchor 1
        {
            const float iw = fmaxf(fminf(tb.z, anc1.z) - fmaxf(tb.x, anc1.x), 0.f);
            const float ih = fmaxf(fminf(tb.w, anc1.w) - fmaxf(tb.y, anc1.y), 0.f);
            const float n = iw * ih;
            const float d = sa1 + st;
            if (n * bd1 > bn1 * d) { bn1 = n; bd1 = d; bt1 = t; }
        }
    }

    float bce = 0.f, sl1 = 0.f, npos = 0.f;

    const int base = b * A;
    const float c0 = cls[base + a0];
    const float c1 = cls[base + a1];
    const float pos0 = (3.f * bn0 > bd0) ? 1.f : 0.f;
    const float pos1 = (3.f * bn1 > bd1) ? 1.f : 0.f;
    // stable softplus, matches jax.nn.softplus
    bce  = (fmaxf(c0, 0.f) + log1pf(expf(-fabsf(c0)))) - c0 * pos0;
    bce += (fmaxf(c1, 0.f) + log1pf(expf(-fabsf(c1)))) - c1 * pos1;
    npos = pos0 + pos1;

    if (pos0 != 0.f) {
        const float4 r  = reinterpret_cast<const float4*>(reg)[base + a0];
        const float4 tb = tgt4[bt0];   // rare, L2-hot
        float e, ae;
        e = r.x - (tb.x - anc0.x); ae = fabsf(e); sl1 += (ae < 1.f) ? 0.5f * e * e : ae - 0.5f;
        e = r.y - (tb.y - anc0.y); ae = fabsf(e); sl1 += (ae < 1.f) ? 0.5f * e * e : ae - 0.5f;
        e = r.z - (tb.z - anc0.z); ae = fabsf(e); sl1 += (ae < 1.f) ? 0.5f * e * e : ae - 0.5f;
        e = r.w - (tb.w - anc0.w); ae = fabsf(e); sl1 += (ae < 1.f) ? 0.5f * e * e : ae - 0.5f;
    }
    if (pos1 != 0.f) {
        const float4 r  = reinterpret_cast<const float4*>(reg)[base + a1];
        const float4 tb = tgt4[bt1];
        float e, ae;
        e = r.x - (tb.x - anc1.x); ae = fabsf(e); sl1 += (ae < 1.f) ? 0.5f * e * e : ae - 0.5f;
        e = r.y - (tb.y - anc1.y); ae = fabsf(e); sl1 += (ae < 1.f) ? 0.5f * e * e : ae - 0.5f;
        e = r.z - (tb.z - anc1.z); ae = fabsf(e); sl1 += (ae < 1.f) ? 0.5f * e * e : ae - 0.5f;
        e = r.w - (tb.w - anc1.w); ae = fabsf(e); sl1 += (ae < 1.f) ? 0.5f * e * e : ae - 0.5f;
    }

    // deterministic block reduction: wave64 shuffle then cross-wave LDS
    for (int off = 32; off > 0; off >>= 1) {
        bce  += __shfl_down(bce,  off, 64);
        sl1  += __shfl_down(sl1,  off, 64);
        npos += __shfl_down(npos, off, 64);
    }
    __shared__ float w_bce[BLOCK / 64], w_sl1[BLOCK / 64], w_np[BLOCK / 64];
    const int lane = threadIdx.x & 63, wid = threadIdx.x >> 6;
    if (lane == 0) { w_bce[wid] = bce; w_sl1[wid] = sl1; w_np[wid] = npos; }
    __syncthreads();
    if (threadIdx.x == 0) {
        float tb_ = 0.f, ts_ = 0.f, tn_ = 0.f;
        for (int w = 0; w < BLOCK / 64; ++w) {
            tb_ += w_bce[w]; ts_ += w_sl1[w]; tn_ += w_np[w];
        }
        partials[blockIdx.x * 3 + 0] = tb_;
        partials[blockIdx.x * 3 + 1] = ts_;
        partials[blockIdx.x * 3 + 2] = tn_;
    }
}

// Kernel 2: single block, double-precision deterministic final reduce (R2 exact).
__global__ void __launch_bounds__(256)
rpn_final(const float* __restrict__ partials, int nblk,
          float* __restrict__ out, int BA) {
    double b = 0.0, s = 0.0, n = 0.0;
    for (int i = threadIdx.x; i < nblk; i += 256) {
        b += (double)partials[i * 3 + 0];
        s += (double)partials[i * 3 + 1];
        n += (double)partials[i * 3 + 2];
    }
    __shared__ double sb[256], ss[256], sn[256];
    sb[threadIdx.x] = b; ss[threadIdx.x] = s; sn[threadIdx.x] = n;
    __syncthreads();
    for (int off = 128; off > 0; off >>= 1) {
        if (threadIdx.x < off) {
            sb[threadIdx.x] += sb[threadIdx.x + off];
            ss[threadIdx.x] += ss[threadIdx.x + off];
            sn[threadIdx.x] += sn[threadIdx.x + off];
        }
        __syncthreads();
    }
    if (threadIdx.x == 0) {
        const double npos = sn[0];
        const double denom = npos > 1.0 ? npos : 1.0;
        const double reg_loss = (npos > 0.0) ? (ss[0] / denom) : 0.0;
        out[0] = (float)(sb[0] / (double)BA);       // cls_loss (mean BCE)
        out[1] = (float)(reg_loss * 0.25);          // reg_loss / 4
    }
}

extern "C" void kernel_launch(void* const* d_in, const int* in_sizes, int n_in,
                              void* d_out, int out_size, void* d_ws, size_t ws_size,
                              hipStream_t stream) {
    const float* reg     = (const float*)d_in[0];
    const float* cls     = (const float*)d_in[1];
    const float* anchors = (const float*)d_in[2];
    const float* targets = (const float*)d_in[3];
    float* out = (float*)d_out;

    const int A = in_sizes[2] / 4;          // anchors [A,4]
    const int B = in_sizes[1] / A;          // cls [B,A]
    const int T = in_sizes[3] / (B * 4);    // targets [B,T,4]
    const int BA = B * A;
    const int nblk = (B * (A / 2)) / BLOCK; // 768 for this shape

    float* partials = (float*)d_ws;         // nblk*3 floats, overwritten every call

    rpn_main<<<nblk, BLOCK, 0, stream>>>(reg, cls, anchors, targets,
                                         partials, A, B, T);
    rpn_final<<<1, 256, 0, stream>>>(partials, nblk, out, BA);
}